// Round 1
// baseline (3793.825 us; speedup 1.0000x reference)
//
#include <hip/hip_runtime.h>
#include <math.h>

#define NN 100000
#define NE 1200000
#define NES (NE + NN)   // edges incl. self-loops
#define FIN 256
#define HID 64
#define NC 32

// ---------------- atomic float max (sign-aware int/uint trick; init = -inf) ----
__device__ __forceinline__ void atomicMaxF(float* addr, float val) {
    if (val >= 0.f) atomicMax((int*)addr, __float_as_int(val));
    else            atomicMin((unsigned int*)addr, __float_as_uint(val));
}

// ---------------- init m=-inf, s=0 --------------------------------------------
__global__ __launch_bounds__(256) void k_init_ms(float* m, float* s) {
    int i = blockIdx.x * 256 + threadIdx.x;
    if (i < NN * 2) { m[i] = -INFINITY; s[i] = 0.f; }
}

// ---------------- degree / dinv -----------------------------------------------
__global__ __launch_bounds__(256) void k_deg(const int* __restrict__ dst,
                                             const float* __restrict__ ew,
                                             float* __restrict__ deg) {
    int e = blockIdx.x * 256 + threadIdx.x;
    if (e >= NES) return;
    int d; float w;
    if (e < NE) { d = dst[e]; w = ew[e]; } else { d = e - NE; w = 1.f; }
    atomicAdd(&deg[d], w);
}
__global__ __launch_bounds__(256) void k_dinv(float* deg) {
    int i = blockIdx.x * 256 + threadIdx.x;
    if (i < NN) { float v = deg[i]; deg[i] = (v > 0.f) ? rsqrtf(v) : 0.f; }
}

// ---------------- pre-linear: xh = x @ W[K,64] + b ----------------------------
__global__ __launch_bounds__(256) void k_gemm_pre(const float* __restrict__ x,
                                                  const float* __restrict__ W,
                                                  const float* __restrict__ b,
                                                  float* __restrict__ xh, int K) {
    int col  = threadIdx.x & 63;
    int rowl = threadIdx.x >> 6;
    int row  = blockIdx.x * 4 + rowl;
    if (row >= NN) return;
    const float* xr = x + (size_t)row * K;
    float acc = 0.f;
    #pragma unroll 8
    for (int k = 0; k < K; ++k) acc += xr[k] * W[k * 64 + col];
    xh[(size_t)row * 64 + col] = acc + b[col];
}

// ---------------- GAT projection: xp = xh @ W[64,128]; a_src/a_dst reductions --
__global__ __launch_bounds__(256) void k_gat_proj(const float* __restrict__ xh,
                                                  const float* __restrict__ W,
                                                  const float* __restrict__ att_s,
                                                  const float* __restrict__ att_d,
                                                  float* __restrict__ xp,
                                                  float* __restrict__ a_src,
                                                  float* __restrict__ a_dst) {
    int col  = threadIdx.x & 127;
    int rowl = threadIdx.x >> 7;
    int row  = blockIdx.x * 2 + rowl;
    if (row >= NN) return;
    const float* xr = xh + (size_t)row * 64;
    float acc = 0.f;
    #pragma unroll
    for (int k = 0; k < 64; ++k) acc += xr[k] * W[k * 128 + col];
    xp[(size_t)row * 128 + col] = acc;
    float vs = acc * att_s[col];   // att flattened [2*64], col = h*64+c
    float vd = acc * att_d[col];
    // each wave (64 lanes) is one (row, head)
    #pragma unroll
    for (int off = 32; off; off >>= 1) {
        vs += __shfl_xor(vs, off);
        vd += __shfl_xor(vd, off);
    }
    if ((threadIdx.x & 63) == 0) {
        int h = col >> 6;
        a_src[row * 2 + h] = vs;
        a_dst[row * 2 + h] = vd;
    }
}

// ---------------- edge scores + segment max -----------------------------------
__global__ __launch_bounds__(256) void k_scores(const int* __restrict__ src,
                                                const int* __restrict__ dst,
                                                const float* __restrict__ a_src,
                                                const float* __restrict__ a_dst,
                                                float* __restrict__ sc,
                                                float* __restrict__ m) {
    int e = blockIdx.x * 256 + threadIdx.x;
    if (e >= NES) return;
    int s_, d_;
    if (e < NE) { s_ = src[e]; d_ = dst[e]; } else { s_ = d_ = e - NE; }
    #pragma unroll
    for (int h = 0; h < 2; ++h) {
        float v = a_src[s_ * 2 + h] + a_dst[d_ * 2 + h];
        v = (v > 0.f) ? v : 0.2f * v;         // GAT leaky slope
        sc[(size_t)e * 2 + h] = v;
        atomicMaxF(&m[d_ * 2 + h], v);
    }
}

// ---------------- exp(score - m) + segment sum --------------------------------
__global__ __launch_bounds__(256) void k_expsum(const int* __restrict__ dst,
                                                const float* __restrict__ m,
                                                float* __restrict__ sc,
                                                float* __restrict__ ssum) {
    int e = blockIdx.x * 256 + threadIdx.x;
    if (e >= NES) return;
    int d_ = (e < NE) ? dst[e] : e - NE;
    #pragma unroll
    for (int h = 0; h < 2; ++h) {
        float ex = __expf(sc[(size_t)e * 2 + h] - m[d_ * 2 + h]);
        sc[(size_t)e * 2 + h] = ex;
        atomicAdd(&ssum[d_ * 2 + h], ex);
    }
}

// ---------------- alpha-weighted scatter of xp into xout[:, 0:128] ------------
__global__ __launch_bounds__(256) void k_gat_accum(const int* __restrict__ src,
                                                   const int* __restrict__ dst,
                                                   const float* __restrict__ sc,
                                                   const float* __restrict__ ssum,
                                                   const float* __restrict__ xp,
                                                   float* __restrict__ xout) {
    long long idx = (long long)blockIdx.x * 256 + threadIdx.x;
    if (idx >= (long long)NES * 128) return;
    int e = (int)(idx >> 7);
    int c = (int)(idx & 127);
    int h = c >> 6;
    int s_, d_;
    if (e < NE) { s_ = src[e]; d_ = dst[e]; } else { s_ = d_ = e - NE; }
    float alpha = sc[(size_t)e * 2 + h] / (ssum[d_ * 2 + h] + 1e-16f);
    atomicAdd(&xout[(size_t)d_ * 192 + c], xp[(size_t)s_ * 128 + c] * alpha);
}

// ---------------- gat bias + relu ---------------------------------------------
__global__ __launch_bounds__(256) void k_gat_final(float* __restrict__ xout,
                                                   const float* __restrict__ gb) {
    int idx = blockIdx.x * 256 + threadIdx.x;
    if (idx >= NN * 128) return;
    int n = idx >> 7, c = idx & 127;
    float v = xout[(size_t)n * 192 + c] + gb[c];
    xout[(size_t)n * 192 + c] = (v > 0.f) ? v : 0.f;
}

// ---------------- SG propagation scatter --------------------------------------
__global__ __launch_bounds__(256) void k_sg_prop(const int* __restrict__ src,
                                                 const int* __restrict__ dst,
                                                 const float* __restrict__ ew,
                                                 const float* __restrict__ dinv,
                                                 const float* __restrict__ xh,
                                                 float* __restrict__ sgh) {
    long long idx = (long long)blockIdx.x * 256 + threadIdx.x;
    if (idx >= (long long)NES * 64) return;
    int e = (int)(idx >> 6);
    int c = (int)(idx & 63);
    int s_, d_; float w;
    if (e < NE) { s_ = src[e]; d_ = dst[e]; w = ew[e]; } else { s_ = d_ = e - NE; w = 1.f; }
    float norm = dinv[s_] * w * dinv[d_];
    atomicAdd(&sgh[(size_t)d_ * 64 + c], xh[(size_t)s_ * 64 + c] * norm);
}

// ---------------- SG linear: xout[:,128:192] = relu(sgh @ W[64,64] + b) -------
__global__ __launch_bounds__(256) void k_sg_gemm(const float* __restrict__ sgh,
                                                 const float* __restrict__ W,
                                                 const float* __restrict__ b,
                                                 float* __restrict__ xout) {
    int col  = threadIdx.x & 63;
    int rowl = threadIdx.x >> 6;
    int row  = blockIdx.x * 4 + rowl;
    if (row >= NN) return;
    const float* xr = sgh + (size_t)row * 64;
    float acc = 0.f;
    #pragma unroll
    for (int k = 0; k < 64; ++k) acc += xr[k] * W[k * 64 + col];
    acc += b[col];
    xout[(size_t)row * 192 + 128 + col] = (acc > 0.f) ? acc : 0.f;
}

// ---------------- classifier + log_softmax ------------------------------------
__global__ __launch_bounds__(256) void k_cls(const float* __restrict__ x,
                                             const float* __restrict__ W,
                                             const float* __restrict__ b,
                                             float* __restrict__ out) {
    int col  = threadIdx.x & 31;
    int rowl = threadIdx.x >> 5;
    int row  = blockIdx.x * 8 + rowl;
    if (row >= NN) return;
    const float* xr = x + (size_t)row * 192;
    float acc = b[col];
    #pragma unroll 8
    for (int k = 0; k < 192; ++k) acc += xr[k] * W[k * 32 + col];
    // reductions within each 32-lane half-wave (one row per half-wave)
    float mx = acc;
    #pragma unroll
    for (int off = 16; off; off >>= 1) mx = fmaxf(mx, __shfl_xor(mx, off));
    float ex = __expf(acc - mx);
    float sm = ex;
    #pragma unroll
    for (int off = 16; off; off >>= 1) sm += __shfl_xor(sm, off);
    out[(size_t)row * 32 + col] = acc - mx - __logf(sm);
}

// ------------------------------------------------------------------------------
extern "C" void kernel_launch(void* const* d_in, const int* in_sizes, int n_in,
                              void* d_out, int out_size, void* d_ws, size_t ws_size,
                              hipStream_t stream) {
    const float* x   = (const float*)d_in[0];
    const int*   ei  = (const int*)d_in[1];
    const float* ew  = (const float*)d_in[2];
    const int* src = ei;
    const int* dst = ei + NE;

    // per-layer params: pre_W, pre_b, gat_W, att_src, att_dst, gat_b, sg_W, sg_b
    const float* P[2][8];
    for (int l = 0; l < 2; ++l)
        for (int j = 0; j < 8; ++j)
            P[l][j] = (const float*)d_in[3 + l * 8 + j];
    const float* cls_W = (const float*)d_in[19];
    const float* cls_b = (const float*)d_in[20];

    float* ws = (float*)d_ws;
    const size_t n = NN;
    float* xh    = ws;                       // 64N
    float* xp    = ws + 64 * n;              // 128N  (sgh aliases first 64N of this)
    float* sgh   = xp;                       // alias: xp dead by the time sgh is used
    float* a_src = ws + 192 * n;             // 2N
    float* a_dst = ws + 194 * n;             // 2N
    float* m     = ws + 196 * n;             // 2N
    float* ssum  = ws + 198 * n;             // 2N
    float* dinv  = ws + 200 * n;             // N
    float* xA    = ws + 201 * n;             // 192N
    float* xB    = ws + 393 * n;             // 192N
    float* sc    = ws + 585 * n;             // 2*NES

    const int TB = 256;
    int gb_edge  = (NES + TB - 1) / TB;

    // degree -> dinv (same for both layers)
    hipMemsetAsync(dinv, 0, n * sizeof(float), stream);
    k_deg <<<gb_edge, TB, 0, stream>>>(dst, ew, dinv);
    k_dinv<<<(NN + TB - 1) / TB, TB, 0, stream>>>(dinv);

    const float* xin = x;
    int K = FIN;
    for (int l = 0; l < 2; ++l) {
        const float* pre_W = P[l][0]; const float* pre_b = P[l][1];
        const float* gat_W = P[l][2]; const float* att_s = P[l][3];
        const float* att_d = P[l][4]; const float* gat_b = P[l][5];
        const float* sg_W  = P[l][6]; const float* sg_b  = P[l][7];
        float* xout = (l == 0) ? xA : xB;

        hipMemsetAsync(xout, 0, n * 192 * sizeof(float), stream);
        k_gemm_pre<<<(NN + 3) / 4, TB, 0, stream>>>(xin, pre_W, pre_b, xh, K);
        k_gat_proj<<<(NN + 1) / 2, TB, 0, stream>>>(xh, gat_W, att_s, att_d,
                                                    xp, a_src, a_dst);
        k_init_ms<<<(NN * 2 + TB - 1) / TB, TB, 0, stream>>>(m, ssum);
        k_scores <<<gb_edge, TB, 0, stream>>>(src, dst, a_src, a_dst, sc, m);
        k_expsum <<<gb_edge, TB, 0, stream>>>(dst, m, sc, ssum);
        {
            long long tot = (long long)NES * 128;
            int blocks = (int)((tot + TB - 1) / TB);
            k_gat_accum<<<blocks, TB, 0, stream>>>(src, dst, sc, ssum, xp, xout);
        }
        k_gat_final<<<(NN * 128 + TB - 1) / TB, TB, 0, stream>>>(xout, gat_b);

        hipMemsetAsync(sgh, 0, n * 64 * sizeof(float), stream);  // xp dead now
        {
            long long tot = (long long)NES * 64;
            int blocks = (int)((tot + TB - 1) / TB);
            k_sg_prop<<<blocks, TB, 0, stream>>>(src, dst, ew, dinv, xh, sgh);
        }
        k_sg_gemm<<<(NN + 3) / 4, TB, 0, stream>>>(sgh, sg_W, sg_b, xout);

        xin = xout;
        K = 192;
    }

    k_cls<<<(NN + 7) / 8, TB, 0, stream>>>(xB, cls_W, cls_b, (float*)d_out);
}

// Round 2
// 2302.719 us; speedup vs baseline: 1.6475x; 1.6475x over previous
//
#include <hip/hip_runtime.h>
#include <math.h>

#define NN 100000
#define NE 1200000
#define NES (NE + NN)   // edges incl. self-loops
#define FIN 256
#define HID 64
#define NC 32
#define NBLK 391        // (NN + 255) / 256

// ---------------- degree / dinv -----------------------------------------------
__global__ __launch_bounds__(256) void k_deg(const int* __restrict__ dst,
                                             const float* __restrict__ ew,
                                             float* __restrict__ deg) {
    int e = blockIdx.x * 256 + threadIdx.x;
    if (e >= NES) return;
    int d; float w;
    if (e < NE) { d = dst[e]; w = ew[e]; } else { d = e - NE; w = 1.f; }
    atomicAdd(&deg[d], w);
}
__global__ __launch_bounds__(256) void k_dinv(float* deg) {
    int i = blockIdx.x * 256 + threadIdx.x;
    if (i < NN) { float v = deg[i]; deg[i] = (v > 0.f) ? rsqrtf(v) : 0.f; }
}

// ---------------- CSR build: histogram, scan, fill ----------------------------
__global__ __launch_bounds__(256) void k_hist(const int* __restrict__ dst,
                                              int* __restrict__ cnt) {
    int e = blockIdx.x * 256 + threadIdx.x;
    if (e >= NES) return;
    int d = (e < NE) ? dst[e] : e - NE;
    atomicAdd(&cnt[d], 1);
}

__global__ __launch_bounds__(256) void k_scanA(int* __restrict__ cnt,
                                               int* __restrict__ row_ptr,
                                               int* __restrict__ bsum) {
    __shared__ int tmp[256];
    int tid = threadIdx.x;
    int i = blockIdx.x * 256 + tid;
    int v = (i < NN) ? cnt[i] : 0;
    if (i < NN) cnt[i] = 0;          // re-zero: cnt becomes the fill cursor
    tmp[tid] = v;
    __syncthreads();
    for (int off = 1; off < 256; off <<= 1) {
        int t = (tid >= off) ? tmp[tid - off] : 0;
        __syncthreads();
        tmp[tid] += t;
        __syncthreads();
    }
    if (i < NN) row_ptr[i] = tmp[tid] - v;   // exclusive within block
    if (tid == 255) bsum[blockIdx.x] = tmp[255];
}

__global__ __launch_bounds__(512) void k_scanB(int* __restrict__ bsum) {
    __shared__ int tmp[512];
    int tid = threadIdx.x;
    int v = (tid < NBLK) ? bsum[tid] : 0;
    tmp[tid] = v;
    __syncthreads();
    for (int off = 1; off < 512; off <<= 1) {
        int t = (tid >= off) ? tmp[tid - off] : 0;
        __syncthreads();
        tmp[tid] += t;
        __syncthreads();
    }
    if (tid < NBLK) bsum[tid] = tmp[tid] - v;  // exclusive block offsets
}

__global__ __launch_bounds__(256) void k_scanC(int* __restrict__ row_ptr,
                                               const int* __restrict__ bsum) {
    int i = blockIdx.x * 256 + threadIdx.x;
    if (i < NN) row_ptr[i] += bsum[i >> 8];
    if (i == 0) row_ptr[NN] = NES;
}

__global__ __launch_bounds__(256) void k_fill(const int* __restrict__ src,
                                              const int* __restrict__ dst,
                                              const float* __restrict__ ew,
                                              const int* __restrict__ row_ptr,
                                              int* __restrict__ cur,
                                              int* __restrict__ src_sorted,
                                              float* __restrict__ w_sorted) {
    int e = blockIdx.x * 256 + threadIdx.x;
    if (e >= NES) return;
    int s, d; float w;
    if (e < NE) { s = src[e]; d = dst[e]; w = ew[e]; } else { s = d = e - NE; w = 1.f; }
    int pos = row_ptr[d] + atomicAdd(&cur[d], 1);
    src_sorted[pos] = s;
    w_sorted[pos] = w;
}

// ---------------- pre-linear: xh = x @ W[K,64] + b ----------------------------
__global__ __launch_bounds__(256) void k_gemm_pre(const float* __restrict__ x,
                                                  const float* __restrict__ W,
                                                  const float* __restrict__ b,
                                                  float* __restrict__ xh, int K) {
    int col  = threadIdx.x & 63;
    int rowl = threadIdx.x >> 6;
    int row  = blockIdx.x * 4 + rowl;
    if (row >= NN) return;
    const float* xr = x + (size_t)row * K;
    float acc = 0.f;
    #pragma unroll 8
    for (int k = 0; k < K; ++k) acc += xr[k] * W[k * 64 + col];
    xh[(size_t)row * 64 + col] = acc + b[col];
}

// ---------------- GAT projection: xp = xh @ W[64,128]; a_src/a_dst reductions --
__global__ __launch_bounds__(256) void k_gat_proj(const float* __restrict__ xh,
                                                  const float* __restrict__ W,
                                                  const float* __restrict__ att_s,
                                                  const float* __restrict__ att_d,
                                                  float* __restrict__ xp,
                                                  float* __restrict__ a_src,
                                                  float* __restrict__ a_dst) {
    int col  = threadIdx.x & 127;
    int rowl = threadIdx.x >> 7;
    int row  = blockIdx.x * 2 + rowl;
    if (row >= NN) return;
    const float* xr = xh + (size_t)row * 64;
    float acc = 0.f;
    #pragma unroll
    for (int k = 0; k < 64; ++k) acc += xr[k] * W[k * 128 + col];
    xp[(size_t)row * 128 + col] = acc;
    float vs = acc * att_s[col];   // att flattened [2*64], col = h*64+c
    float vd = acc * att_d[col];
    #pragma unroll
    for (int off = 32; off; off >>= 1) {
        vs += __shfl_xor(vs, off);
        vd += __shfl_xor(vd, off);
    }
    if ((threadIdx.x & 63) == 0) {
        int h = col >> 6;
        a_src[row * 2 + h] = vs;
        a_dst[row * 2 + h] = vd;
    }
}

// ---------------- fused GAT aggregation: one wave per dst node ----------------
__global__ __launch_bounds__(256) void k_gat_node(const int* __restrict__ row_ptr,
                                                  const int* __restrict__ src_sorted,
                                                  const float* __restrict__ a_src,
                                                  const float* __restrict__ a_dst,
                                                  const float* __restrict__ xp,
                                                  const float* __restrict__ gb,
                                                  float* __restrict__ xout) {
    int lane = threadIdx.x & 63;
    int d = blockIdx.x * 4 + (threadIdx.x >> 6);
    if (d >= NN) return;
    int p0 = row_ptr[d], p1 = row_ptr[d + 1];
    float ad0 = a_dst[2 * d], ad1 = a_dst[2 * d + 1];

    // pass 1: segment max (lane-strided, wave-reduced)
    float m0 = -INFINITY, m1 = -INFINITY;
    for (int e = p0 + lane; e < p1; e += 64) {
        int s = src_sorted[e];
        float v0 = a_src[2 * s] + ad0;     v0 = (v0 > 0.f) ? v0 : 0.2f * v0;
        float v1 = a_src[2 * s + 1] + ad1; v1 = (v1 > 0.f) ? v1 : 0.2f * v1;
        m0 = fmaxf(m0, v0); m1 = fmaxf(m1, v1);
    }
    #pragma unroll
    for (int off = 32; off; off >>= 1) {
        m0 = fmaxf(m0, __shfl_xor(m0, off));
        m1 = fmaxf(m1, __shfl_xor(m1, off));
    }

    // pass 2: segment sum of exp
    float s0 = 0.f, s1 = 0.f;
    for (int e = p0 + lane; e < p1; e += 64) {
        int s = src_sorted[e];
        float v0 = a_src[2 * s] + ad0;     v0 = (v0 > 0.f) ? v0 : 0.2f * v0;
        float v1 = a_src[2 * s + 1] + ad1; v1 = (v1 > 0.f) ? v1 : 0.2f * v1;
        s0 += __expf(v0 - m0); s1 += __expf(v1 - m1);
    }
    #pragma unroll
    for (int off = 32; off; off >>= 1) {
        s0 += __shfl_xor(s0, off);
        s1 += __shfl_xor(s1, off);
    }
    float inv0 = 1.f / (s0 + 1e-16f), inv1 = 1.f / (s1 + 1e-16f);

    // pass 3: alpha-weighted gather of xp rows (edge loop sequential per wave)
    float acc0 = 0.f, acc1 = 0.f;
    for (int e = p0; e < p1; ++e) {
        int s = src_sorted[e];
        float v0 = a_src[2 * s] + ad0;     v0 = (v0 > 0.f) ? v0 : 0.2f * v0;
        float v1 = a_src[2 * s + 1] + ad1; v1 = (v1 > 0.f) ? v1 : 0.2f * v1;
        float al0 = __expf(v0 - m0) * inv0;
        float al1 = __expf(v1 - m1) * inv1;
        acc0 += al0 * xp[(size_t)s * 128 + lane];
        acc1 += al1 * xp[(size_t)s * 128 + 64 + lane];
    }
    float r0 = acc0 + gb[lane];
    float r1 = acc1 + gb[64 + lane];
    xout[(size_t)d * 192 + lane]      = (r0 > 0.f) ? r0 : 0.f;  // relu(leaky(v,.01))==relu(v)
    xout[(size_t)d * 192 + 64 + lane] = (r1 > 0.f) ? r1 : 0.f;
}

// ---------------- fused SG propagation: one wave per dst node -----------------
__global__ __launch_bounds__(256) void k_sg_node(const int* __restrict__ row_ptr,
                                                 const int* __restrict__ src_sorted,
                                                 const float* __restrict__ w_sorted,
                                                 const float* __restrict__ dinv,
                                                 const float* __restrict__ xh,
                                                 float* __restrict__ sgh) {
    int lane = threadIdx.x & 63;
    int d = blockIdx.x * 4 + (threadIdx.x >> 6);
    if (d >= NN) return;
    int p0 = row_ptr[d], p1 = row_ptr[d + 1];
    float did = dinv[d];
    float acc = 0.f;
    for (int e = p0; e < p1; ++e) {
        int s = src_sorted[e];
        float nrm = did * w_sorted[e] * dinv[s];
        acc += nrm * xh[(size_t)s * 64 + lane];
    }
    sgh[(size_t)d * 64 + lane] = acc;
}

// ---------------- SG linear: xout[:,128:192] = relu(sgh @ W[64,64] + b) -------
__global__ __launch_bounds__(256) void k_sg_gemm(const float* __restrict__ sgh,
                                                 const float* __restrict__ W,
                                                 const float* __restrict__ b,
                                                 float* __restrict__ xout) {
    int col  = threadIdx.x & 63;
    int rowl = threadIdx.x >> 6;
    int row  = blockIdx.x * 4 + rowl;
    if (row >= NN) return;
    const float* xr = sgh + (size_t)row * 64;
    float acc = 0.f;
    #pragma unroll
    for (int k = 0; k < 64; ++k) acc += xr[k] * W[k * 64 + col];
    acc += b[col];
    xout[(size_t)row * 192 + 128 + col] = (acc > 0.f) ? acc : 0.f;
}

// ---------------- classifier + log_softmax ------------------------------------
__global__ __launch_bounds__(256) void k_cls(const float* __restrict__ x,
                                             const float* __restrict__ W,
                                             const float* __restrict__ b,
                                             float* __restrict__ out) {
    int col  = threadIdx.x & 31;
    int rowl = threadIdx.x >> 5;
    int row  = blockIdx.x * 8 + rowl;
    if (row >= NN) return;
    const float* xr = x + (size_t)row * 192;
    float acc = b[col];
    #pragma unroll 8
    for (int k = 0; k < 192; ++k) acc += xr[k] * W[k * 32 + col];
    float mx = acc;
    #pragma unroll
    for (int off = 16; off; off >>= 1) mx = fmaxf(mx, __shfl_xor(mx, off));
    float ex = __expf(acc - mx);
    float sm = ex;
    #pragma unroll
    for (int off = 16; off; off >>= 1) sm += __shfl_xor(sm, off);
    out[(size_t)row * 32 + col] = acc - mx - __logf(sm);
}

// ------------------------------------------------------------------------------
extern "C" void kernel_launch(void* const* d_in, const int* in_sizes, int n_in,
                              void* d_out, int out_size, void* d_ws, size_t ws_size,
                              hipStream_t stream) {
    const float* x   = (const float*)d_in[0];
    const int*   ei  = (const int*)d_in[1];
    const float* ew  = (const float*)d_in[2];
    const int* src = ei;
    const int* dst = ei + NE;

    const float* P[2][8];
    for (int l = 0; l < 2; ++l)
        for (int j = 0; j < 8; ++j)
            P[l][j] = (const float*)d_in[3 + l * 8 + j];
    const float* cls_W = (const float*)d_in[19];
    const float* cls_b = (const float*)d_in[20];

    float* ws = (float*)d_ws;
    const size_t n = NN;
    float* xh    = ws;                       // 64N
    float* xp    = ws + 64 * n;              // 128N (sgh aliases: xp dead when sgh live)
    float* sgh   = xp;
    float* a_src = ws + 192 * n;             // 2N
    float* a_dst = ws + 194 * n;             // 2N
    float* dinv  = ws + 196 * n;             // N
    float* xA    = ws + 197 * n;             // 192N
    float* xB    = ws + 389 * n;             // 192N
    int*   row_ptr    = (int*)(ws + 581 * n);        // NN+1
    int*   cnt        = row_ptr + (NN + 1);          // NN (histogram, then cursor)
    int*   bsum       = cnt + NN;                    // 512
    int*   src_sorted = bsum + 512;                  // NES
    float* w_sorted   = (float*)(src_sorted + NES);  // NES

    const int TB = 256;
    int gb_edge = (NES + TB - 1) / TB;
    int gb_node = (NN + TB - 1) / TB;
    int gb_wave4 = (NN + 3) / 4;   // kernels with one wave per node

    // ---- CSR build (per call: ws is re-poisoned) ----
    hipMemsetAsync(cnt, 0, NN * sizeof(int), stream);
    k_hist <<<gb_edge, TB, 0, stream>>>(dst, cnt);
    k_scanA<<<NBLK, TB, 0, stream>>>(cnt, row_ptr, bsum);
    k_scanB<<<1, 512, 0, stream>>>(bsum);
    k_scanC<<<gb_node, TB, 0, stream>>>(row_ptr, bsum);
    k_fill <<<gb_edge, TB, 0, stream>>>(src, dst, ew, row_ptr, cnt, src_sorted, w_sorted);

    // ---- degree -> dinv ----
    hipMemsetAsync(dinv, 0, n * sizeof(float), stream);
    k_deg <<<gb_edge, TB, 0, stream>>>(dst, ew, dinv);
    k_dinv<<<gb_node, TB, 0, stream>>>(dinv);

    const float* xin = x;
    int K = FIN;
    for (int l = 0; l < 2; ++l) {
        const float* pre_W = P[l][0]; const float* pre_b = P[l][1];
        const float* gat_W = P[l][2]; const float* att_s = P[l][3];
        const float* att_d = P[l][4]; const float* gat_b = P[l][5];
        const float* sg_W  = P[l][6]; const float* sg_b  = P[l][7];
        float* xout = (l == 0) ? xA : xB;

        k_gemm_pre<<<gb_wave4, TB, 0, stream>>>(xin, pre_W, pre_b, xh, K);
        k_gat_proj<<<(NN + 1) / 2, TB, 0, stream>>>(xh, gat_W, att_s, att_d,
                                                    xp, a_src, a_dst);
        k_gat_node<<<gb_wave4, TB, 0, stream>>>(row_ptr, src_sorted, a_src, a_dst,
                                                xp, gat_b, xout);
        k_sg_node <<<gb_wave4, TB, 0, stream>>>(row_ptr, src_sorted, w_sorted, dinv,
                                                xh, sgh);
        k_sg_gemm <<<gb_wave4, TB, 0, stream>>>(sgh, sg_W, sg_b, xout);

        xin = xout;
        K = 192;
    }

    k_cls<<<(NN + 7) / 8, TB, 0, stream>>>(xB, cls_W, cls_b, (float*)d_out);
}

// Round 3
// 1292.974 us; speedup vs baseline: 2.9342x; 1.7809x over previous
//
#include <hip/hip_runtime.h>
#include <math.h>

#define NN 100000
#define NE 1200000
#define NES (NE + NN)   // edges incl. self-loops
#define FIN 256
#define HID 64
#define NC 32
#define NBLK 391        // (NN + 255) / 256

// ---------------- degree / dinv -----------------------------------------------
__global__ __launch_bounds__(256) void k_deg(const int* __restrict__ dst,
                                             const float* __restrict__ ew,
                                             float* __restrict__ deg) {
    int e = blockIdx.x * 256 + threadIdx.x;
    if (e >= NES) return;
    int d; float w;
    if (e < NE) { d = dst[e]; w = ew[e]; } else { d = e - NE; w = 1.f; }
    atomicAdd(&deg[d], w);
}
__global__ __launch_bounds__(256) void k_dinv(float* deg) {
    int i = blockIdx.x * 256 + threadIdx.x;
    if (i < NN) { float v = deg[i]; deg[i] = (v > 0.f) ? rsqrtf(v) : 0.f; }
}

// ---------------- CSR build: histogram, scan, fill ----------------------------
__global__ __launch_bounds__(256) void k_hist(const int* __restrict__ dst,
                                              int* __restrict__ cnt) {
    int e = blockIdx.x * 256 + threadIdx.x;
    if (e >= NES) return;
    int d = (e < NE) ? dst[e] : e - NE;
    atomicAdd(&cnt[d], 1);
}

__global__ __launch_bounds__(256) void k_scanA(int* __restrict__ cnt,
                                               int* __restrict__ row_ptr,
                                               int* __restrict__ bsum) {
    __shared__ int tmp[256];
    int tid = threadIdx.x;
    int i = blockIdx.x * 256 + tid;
    int v = (i < NN) ? cnt[i] : 0;
    if (i < NN) cnt[i] = 0;          // re-zero: cnt becomes the fill cursor
    tmp[tid] = v;
    __syncthreads();
    for (int off = 1; off < 256; off <<= 1) {
        int t = (tid >= off) ? tmp[tid - off] : 0;
        __syncthreads();
        tmp[tid] += t;
        __syncthreads();
    }
    if (i < NN) row_ptr[i] = tmp[tid] - v;   // exclusive within block
    if (tid == 255) bsum[blockIdx.x] = tmp[255];
}

__global__ __launch_bounds__(512) void k_scanB(int* __restrict__ bsum) {
    __shared__ int tmp[512];
    int tid = threadIdx.x;
    int v = (tid < NBLK) ? bsum[tid] : 0;
    tmp[tid] = v;
    __syncthreads();
    for (int off = 1; off < 512; off <<= 1) {
        int t = (tid >= off) ? tmp[tid - off] : 0;
        __syncthreads();
        tmp[tid] += t;
        __syncthreads();
    }
    if (tid < NBLK) bsum[tid] = tmp[tid] - v;  // exclusive block offsets
}

__global__ __launch_bounds__(256) void k_scanC(int* __restrict__ row_ptr,
                                               const int* __restrict__ bsum) {
    int i = blockIdx.x * 256 + threadIdx.x;
    if (i < NN) row_ptr[i] += bsum[i >> 8];
    if (i == 0) row_ptr[NN] = NES;
}

__global__ __launch_bounds__(256) void k_fill(const int* __restrict__ src,
                                              const int* __restrict__ dst,
                                              const float* __restrict__ ew,
                                              const int* __restrict__ row_ptr,
                                              int* __restrict__ cur,
                                              int* __restrict__ src_sorted,
                                              float* __restrict__ w_sorted) {
    int e = blockIdx.x * 256 + threadIdx.x;
    if (e >= NES) return;
    int s, d; float w;
    if (e < NE) { s = src[e]; d = dst[e]; w = ew[e]; } else { s = d = e - NE; w = 1.f; }
    int pos = row_ptr[d] + atomicAdd(&cur[d], 1);
    src_sorted[pos] = s;
    w_sorted[pos] = w;
}

// ---------------- tiled GEMM core: C[M,N] = A[M,K] @ W[K,N] -------------------
// 256 threads, per-thread 4x4 tile. TX=N/4 col-threads, TY=256/TX row-threads,
// ROWS=4*TY rows per block. K chunked by 32. A staged [ROWS][36] (16B-aligned
// rows, non-pow2 stride); W staged [32][N].
template<int N>
__device__ __forceinline__ void gemm_core(const float* __restrict__ A,
                                          const float* __restrict__ W,
                                          int K, int row0,
                                          float* __restrict__ As,
                                          float* __restrict__ Ws,
                                          float acc[4][4]) {
    constexpr int TX = N / 4;
    constexpr int ROWS = 4 * (256 / TX);
    const int tid = threadIdx.x;
    const int tx = tid % TX, ty = tid / TX;
    #pragma unroll
    for (int i = 0; i < 4; ++i)
        #pragma unroll
        for (int j = 0; j < 4; ++j) acc[i][j] = 0.f;
    for (int kc = 0; kc < K; kc += 32) {
        __syncthreads();
        for (int i = tid; i < ROWS * 32; i += 256) {
            int r = i >> 5, kl = i & 31;
            int gr = row0 + r; if (gr > NN - 1) gr = NN - 1;
            As[r * 36 + kl] = A[(size_t)gr * K + kc + kl];
        }
        for (int i = tid; i < 32 * N; i += 256)
            Ws[i] = W[(size_t)kc * N + i];
        __syncthreads();
        #pragma unroll
        for (int kl = 0; kl < 32; kl += 4) {
            float4 a[4], w[4];
            #pragma unroll
            for (int i = 0; i < 4; ++i)
                a[i] = *(const float4*)&As[(4 * ty + i) * 36 + kl];
            #pragma unroll
            for (int t = 0; t < 4; ++t)
                w[t] = *(const float4*)&Ws[(kl + t) * N + 4 * tx];
            #pragma unroll
            for (int i = 0; i < 4; ++i) {
                const float* af = (const float*)&a[i];
                #pragma unroll
                for (int t = 0; t < 4; ++t) {
                    float s = af[t];
                    const float* wf = (const float*)&w[t];
                    acc[i][0] = fmaf(s, wf[0], acc[i][0]);
                    acc[i][1] = fmaf(s, wf[1], acc[i][1]);
                    acc[i][2] = fmaf(s, wf[2], acc[i][2]);
                    acc[i][3] = fmaf(s, wf[3], acc[i][3]);
                }
            }
        }
    }
}

// ---------------- pre-linear: xh = x @ W[K,64] + b (64 rows/block) ------------
__global__ __launch_bounds__(256) void k_pre(const float* __restrict__ A,
                                             const float* __restrict__ W,
                                             const float* __restrict__ b,
                                             float* __restrict__ out, int K) {
    __shared__ __align__(16) float As[64 * 36];
    __shared__ __align__(16) float Ws[32 * 64];
    float acc[4][4];
    int row0 = blockIdx.x * 64;
    gemm_core<64>(A, W, K, row0, As, Ws, acc);
    int tx = threadIdx.x % 16, ty = threadIdx.x / 16;
    float4 bb = *(const float4*)&b[tx * 4];
    #pragma unroll
    for (int i = 0; i < 4; ++i) {
        int row = row0 + 4 * ty + i;
        if (row < NN) {
            float4 o = { acc[i][0] + bb.x, acc[i][1] + bb.y,
                         acc[i][2] + bb.z, acc[i][3] + bb.w };
            *(float4*)&out[(size_t)row * 64 + tx * 4] = o;
        }
    }
}

// ---------------- GAT projection + attention scores (32 rows/block) -----------
__global__ __launch_bounds__(256) void k_proj(const float* __restrict__ xh,
                                              const float* __restrict__ W,
                                              const float* __restrict__ att_s,
                                              const float* __restrict__ att_d,
                                              float* __restrict__ xp,
                                              float* __restrict__ a_src,
                                              float* __restrict__ a_dst) {
    __shared__ __align__(16) float As[32 * 36];
    __shared__ __align__(16) float Ws[32 * 128];
    float acc[4][4];
    int row0 = blockIdx.x * 32;
    gemm_core<128>(xh, W, 64, row0, As, Ws, acc);
    int tx = threadIdx.x % 32, ty = threadIdx.x / 32;
    int col = tx * 4, h = tx >> 4;
    float4 s4 = *(const float4*)&att_s[col];
    float4 d4 = *(const float4*)&att_d[col];
    float vs[4], vd[4];
    #pragma unroll
    for (int i = 0; i < 4; ++i) {
        int row = row0 + 4 * ty + i;
        if (row < NN)
            *(float4*)&xp[(size_t)row * 128 + col] =
                *(float4*)&acc[i][0];
        vs[i] = acc[i][0] * s4.x + acc[i][1] * s4.y + acc[i][2] * s4.z + acc[i][3] * s4.w;
        vd[i] = acc[i][0] * d4.x + acc[i][1] * d4.y + acc[i][2] * d4.z + acc[i][3] * d4.w;
    }
    #pragma unroll
    for (int off = 1; off < 16; off <<= 1) {
        #pragma unroll
        for (int i = 0; i < 4; ++i) {
            vs[i] += __shfl_xor(vs[i], off);
            vd[i] += __shfl_xor(vd[i], off);
        }
    }
    if ((tx & 15) == 0) {
        #pragma unroll
        for (int i = 0; i < 4; ++i) {
            int row = row0 + 4 * ty + i;
            if (row < NN) {
                a_src[row * 2 + h] = vs[i];
                a_dst[row * 2 + h] = vd[i];
            }
        }
    }
}

// ---------------- SG linear (64 rows/block) -----------------------------------
__global__ __launch_bounds__(256) void k_sgg(const float* __restrict__ sgh,
                                             const float* __restrict__ W,
                                             const float* __restrict__ b,
                                             float* __restrict__ xout) {
    __shared__ __align__(16) float As[64 * 36];
    __shared__ __align__(16) float Ws[32 * 64];
    float acc[4][4];
    int row0 = blockIdx.x * 64;
    gemm_core<64>(sgh, W, 64, row0, As, Ws, acc);
    int tx = threadIdx.x % 16, ty = threadIdx.x / 16;
    float4 bb = *(const float4*)&b[tx * 4];
    #pragma unroll
    for (int i = 0; i < 4; ++i) {
        int row = row0 + 4 * ty + i;
        if (row < NN) {
            float4 o;
            o.x = fmaxf(acc[i][0] + bb.x, 0.f);
            o.y = fmaxf(acc[i][1] + bb.y, 0.f);
            o.z = fmaxf(acc[i][2] + bb.z, 0.f);
            o.w = fmaxf(acc[i][3] + bb.w, 0.f);
            *(float4*)&xout[(size_t)row * 192 + 128 + tx * 4] = o;
        }
    }
}

// ---------------- classifier + log_softmax (128 rows/block) -------------------
__global__ __launch_bounds__(256) void k_cls(const float* __restrict__ x,
                                             const float* __restrict__ W,
                                             const float* __restrict__ b,
                                             float* __restrict__ out) {
    __shared__ __align__(16) float As[128 * 36];
    __shared__ __align__(16) float Ws[32 * 32];
    float acc[4][4];
    int row0 = blockIdx.x * 128;
    gemm_core<32>(x, W, 192, row0, As, Ws, acc);
    int tx = threadIdx.x % 8, ty = threadIdx.x / 8;
    float4 b4 = *(const float4*)&b[tx * 4];
    #pragma unroll
    for (int i = 0; i < 4; ++i) {
        int row = row0 + 4 * ty + i;
        float v0 = acc[i][0] + b4.x, v1 = acc[i][1] + b4.y;
        float v2 = acc[i][2] + b4.z, v3 = acc[i][3] + b4.w;
        float mx = fmaxf(fmaxf(v0, v1), fmaxf(v2, v3));
        #pragma unroll
        for (int off = 1; off < 8; off <<= 1) mx = fmaxf(mx, __shfl_xor(mx, off));
        float sm = __expf(v0 - mx) + __expf(v1 - mx) + __expf(v2 - mx) + __expf(v3 - mx);
        #pragma unroll
        for (int off = 1; off < 8; off <<= 1) sm += __shfl_xor(sm, off);
        float lg = mx + __logf(sm);
        if (row < NN) {
            float4 o = { v0 - lg, v1 - lg, v2 - lg, v3 - lg };
            *(float4*)&out[(size_t)row * 32 + tx * 4] = o;
        }
    }
}

// ---------------- fused GAT aggregation: one wave per dst node ----------------
__global__ __launch_bounds__(256) void k_gat_node(const int* __restrict__ row_ptr,
                                                  const int* __restrict__ src_sorted,
                                                  const float* __restrict__ a_src,
                                                  const float* __restrict__ a_dst,
                                                  const float* __restrict__ xp,
                                                  const float* __restrict__ gb,
                                                  float* __restrict__ xout) {
    int lane = threadIdx.x & 63;
    int d = blockIdx.x * 4 + (threadIdx.x >> 6);
    if (d >= NN) return;
    int p0 = row_ptr[d], p1 = row_ptr[d + 1];
    float ad0 = a_dst[2 * d], ad1 = a_dst[2 * d + 1];

    float m0 = -INFINITY, m1 = -INFINITY;
    for (int e = p0 + lane; e < p1; e += 64) {
        int s = src_sorted[e];
        float v0 = a_src[2 * s] + ad0;     v0 = (v0 > 0.f) ? v0 : 0.2f * v0;
        float v1 = a_src[2 * s + 1] + ad1; v1 = (v1 > 0.f) ? v1 : 0.2f * v1;
        m0 = fmaxf(m0, v0); m1 = fmaxf(m1, v1);
    }
    #pragma unroll
    for (int off = 32; off; off >>= 1) {
        m0 = fmaxf(m0, __shfl_xor(m0, off));
        m1 = fmaxf(m1, __shfl_xor(m1, off));
    }

    float s0 = 0.f, s1 = 0.f;
    for (int e = p0 + lane; e < p1; e += 64) {
        int s = src_sorted[e];
        float v0 = a_src[2 * s] + ad0;     v0 = (v0 > 0.f) ? v0 : 0.2f * v0;
        float v1 = a_src[2 * s + 1] + ad1; v1 = (v1 > 0.f) ? v1 : 0.2f * v1;
        s0 += __expf(v0 - m0); s1 += __expf(v1 - m1);
    }
    #pragma unroll
    for (int off = 32; off; off >>= 1) {
        s0 += __shfl_xor(s0, off);
        s1 += __shfl_xor(s1, off);
    }
    float inv0 = 1.f / (s0 + 1e-16f), inv1 = 1.f / (s1 + 1e-16f);

    float acc0 = 0.f, acc1 = 0.f;
    for (int e = p0; e < p1; ++e) {
        int s = src_sorted[e];
        float v0 = a_src[2 * s] + ad0;     v0 = (v0 > 0.f) ? v0 : 0.2f * v0;
        float v1 = a_src[2 * s + 1] + ad1; v1 = (v1 > 0.f) ? v1 : 0.2f * v1;
        float al0 = __expf(v0 - m0) * inv0;
        float al1 = __expf(v1 - m1) * inv1;
        acc0 += al0 * xp[(size_t)s * 128 + lane];
        acc1 += al1 * xp[(size_t)s * 128 + 64 + lane];
    }
    float r0 = acc0 + gb[lane];
    float r1 = acc1 + gb[64 + lane];
    xout[(size_t)d * 192 + lane]      = (r0 > 0.f) ? r0 : 0.f;
    xout[(size_t)d * 192 + 64 + lane] = (r1 > 0.f) ? r1 : 0.f;
}

// ---------------- fused SG propagation: one wave per dst node -----------------
__global__ __launch_bounds__(256) void k_sg_node(const int* __restrict__ row_ptr,
                                                 const int* __restrict__ src_sorted,
                                                 const float* __restrict__ w_sorted,
                                                 const float* __restrict__ dinv,
                                                 const float* __restrict__ xh,
                                                 float* __restrict__ sgh) {
    int lane = threadIdx.x & 63;
    int d = blockIdx.x * 4 + (threadIdx.x >> 6);
    if (d >= NN) return;
    int p0 = row_ptr[d], p1 = row_ptr[d + 1];
    float did = dinv[d];
    float acc = 0.f;
    for (int e = p0; e < p1; ++e) {
        int s = src_sorted[e];
        float nrm = did * w_sorted[e] * dinv[s];
        acc += nrm * xh[(size_t)s * 64 + lane];
    }
    sgh[(size_t)d * 64 + lane] = acc;
}

// ------------------------------------------------------------------------------
extern "C" void kernel_launch(void* const* d_in, const int* in_sizes, int n_in,
                              void* d_out, int out_size, void* d_ws, size_t ws_size,
                              hipStream_t stream) {
    const float* x   = (const float*)d_in[0];
    const int*   ei  = (const int*)d_in[1];
    const float* ew  = (const float*)d_in[2];
    const int* src = ei;
    const int* dst = ei + NE;

    const float* P[2][8];
    for (int l = 0; l < 2; ++l)
        for (int j = 0; j < 8; ++j)
            P[l][j] = (const float*)d_in[3 + l * 8 + j];
    const float* cls_W = (const float*)d_in[19];
    const float* cls_b = (const float*)d_in[20];

    float* ws = (float*)d_ws;
    const size_t n = NN;
    float* xh    = ws;                       // 64N
    float* xp    = ws + 64 * n;              // 128N (sgh aliases: xp dead when sgh live)
    float* sgh   = xp;
    float* a_src = ws + 192 * n;             // 2N
    float* a_dst = ws + 194 * n;             // 2N
    float* dinv  = ws + 196 * n;             // N
    float* xA    = ws + 197 * n;             // 192N
    float* xB    = ws + 389 * n;             // 192N
    int*   row_ptr    = (int*)(ws + 581 * n);        // NN+1
    int*   cnt        = row_ptr + (NN + 1);          // NN (histogram, then cursor)
    int*   bsum       = cnt + NN;                    // 512
    int*   src_sorted = bsum + 512;                  // NES
    float* w_sorted   = (float*)(src_sorted + NES);  // NES

    const int TB = 256;
    int gb_edge = (NES + TB - 1) / TB;
    int gb_node = (NN + TB - 1) / TB;
    int gb_wave4 = (NN + 3) / 4;

    // ---- CSR build ----
    hipMemsetAsync(cnt, 0, NN * sizeof(int), stream);
    k_hist <<<gb_edge, TB, 0, stream>>>(dst, cnt);
    k_scanA<<<NBLK, TB, 0, stream>>>(cnt, row_ptr, bsum);
    k_scanB<<<1, 512, 0, stream>>>(bsum);
    k_scanC<<<gb_node, TB, 0, stream>>>(row_ptr, bsum);
    k_fill <<<gb_edge, TB, 0, stream>>>(src, dst, ew, row_ptr, cnt, src_sorted, w_sorted);

    // ---- degree -> dinv ----
    hipMemsetAsync(dinv, 0, n * sizeof(float), stream);
    k_deg <<<gb_edge, TB, 0, stream>>>(dst, ew, dinv);
    k_dinv<<<gb_node, TB, 0, stream>>>(dinv);

    const float* xin = x;
    int K = FIN;
    for (int l = 0; l < 2; ++l) {
        const float* pre_W = P[l][0]; const float* pre_b = P[l][1];
        const float* gat_W = P[l][2]; const float* att_s = P[l][3];
        const float* att_d = P[l][4]; const float* gat_b = P[l][5];
        const float* sg_W  = P[l][6]; const float* sg_b  = P[l][7];
        float* xout = (l == 0) ? xA : xB;

        k_pre <<<(NN + 63) / 64, TB, 0, stream>>>(xin, pre_W, pre_b, xh, K);
        k_proj<<<(NN + 31) / 32, TB, 0, stream>>>(xh, gat_W, att_s, att_d,
                                                  xp, a_src, a_dst);
        k_gat_node<<<gb_wave4, TB, 0, stream>>>(row_ptr, src_sorted, a_src, a_dst,
                                                xp, gat_b, xout);
        k_sg_node <<<gb_wave4, TB, 0, stream>>>(row_ptr, src_sorted, w_sorted, dinv,
                                                xh, sgh);
        k_sgg <<<(NN + 63) / 64, TB, 0, stream>>>(sgh, sg_W, sg_b, xout);

        xin = xout;
        K = 192;
    }

    k_cls<<<(NN + 127) / 128, TB, 0, stream>>>(xB, cls_W, cls_b, (float*)d_out);
}

// Round 4
// 1108.000 us; speedup vs baseline: 3.4240x; 1.1669x over previous
//
#include <hip/hip_runtime.h>
#include <hip/hip_fp16.h>
#include <math.h>

#define NN 100000
#define NE 1200000
#define NES (NE + NN)   // edges incl. self-loops
#define FIN 256
#define HID 64
#define NC 32
#define NBLK 391        // (NN + 255) / 256

// ---------------- fused histogram + degree ------------------------------------
__global__ __launch_bounds__(256) void k_histdeg(const int* __restrict__ dst,
                                                 const float* __restrict__ ew,
                                                 int* __restrict__ cnt,
                                                 float* __restrict__ deg) {
    int e = blockIdx.x * 256 + threadIdx.x;
    if (e >= NES) return;
    int d; float w;
    if (e < NE) { d = dst[e]; w = ew[e]; } else { d = e - NE; w = 1.f; }
    atomicAdd(&cnt[d], 1);
    atomicAdd(&deg[d], w);
}
__global__ __launch_bounds__(256) void k_dinv(float* deg) {
    int i = blockIdx.x * 256 + threadIdx.x;
    if (i < NN) { float v = deg[i]; deg[i] = (v > 0.f) ? rsqrtf(v) : 0.f; }
}

// ---------------- CSR build: scan, fill ---------------------------------------
__global__ __launch_bounds__(256) void k_scanA(int* __restrict__ cnt,
                                               int* __restrict__ row_ptr,
                                               int* __restrict__ bsum) {
    __shared__ int tmp[256];
    int tid = threadIdx.x;
    int i = blockIdx.x * 256 + tid;
    int v = (i < NN) ? cnt[i] : 0;
    if (i < NN) cnt[i] = 0;          // re-zero: cnt becomes the fill cursor
    tmp[tid] = v;
    __syncthreads();
    for (int off = 1; off < 256; off <<= 1) {
        int t = (tid >= off) ? tmp[tid - off] : 0;
        __syncthreads();
        tmp[tid] += t;
        __syncthreads();
    }
    if (i < NN) row_ptr[i] = tmp[tid] - v;   // exclusive within block
    if (tid == 255) bsum[blockIdx.x] = tmp[255];
}

__global__ __launch_bounds__(512) void k_scanB(int* __restrict__ bsum) {
    __shared__ int tmp[512];
    int tid = threadIdx.x;
    int v = (tid < NBLK) ? bsum[tid] : 0;
    tmp[tid] = v;
    __syncthreads();
    for (int off = 1; off < 512; off <<= 1) {
        int t = (tid >= off) ? tmp[tid - off] : 0;
        __syncthreads();
        tmp[tid] += t;
        __syncthreads();
    }
    if (tid < NBLK) bsum[tid] = tmp[tid] - v;  // exclusive block offsets
}

__global__ __launch_bounds__(256) void k_scanC(int* __restrict__ row_ptr,
                                               const int* __restrict__ bsum) {
    int i = blockIdx.x * 256 + threadIdx.x;
    if (i < NN) row_ptr[i] += bsum[i >> 8];
    if (i == 0) row_ptr[NN] = NES;
}

__global__ __launch_bounds__(256) void k_fill(const int* __restrict__ src,
                                              const int* __restrict__ dst,
                                              const float* __restrict__ ew,
                                              const int* __restrict__ row_ptr,
                                              int* __restrict__ cur,
                                              int* __restrict__ src_sorted,
                                              float* __restrict__ w_sorted) {
    int e = blockIdx.x * 256 + threadIdx.x;
    if (e >= NES) return;
    int s, d; float w;
    if (e < NE) { s = src[e]; d = dst[e]; w = ew[e]; } else { s = d = e - NE; w = 1.f; }
    int pos = row_ptr[d] + atomicAdd(&cur[d], 1);
    src_sorted[pos] = s;
    w_sorted[pos] = w;
}

// ---------------- tiled GEMM core: C[M,N] = A[M,K] @ W[K,N] -------------------
template<int N>
__device__ __forceinline__ void gemm_core(const float* __restrict__ A,
                                          const float* __restrict__ W,
                                          int K, int row0,
                                          float* __restrict__ As,
                                          float* __restrict__ Ws,
                                          float acc[4][4]) {
    constexpr int TX = N / 4;
    constexpr int ROWS = 4 * (256 / TX);
    const int tid = threadIdx.x;
    const int tx = tid % TX, ty = tid / TX;
    #pragma unroll
    for (int i = 0; i < 4; ++i)
        #pragma unroll
        for (int j = 0; j < 4; ++j) acc[i][j] = 0.f;
    for (int kc = 0; kc < K; kc += 32) {
        __syncthreads();
        for (int i = tid; i < ROWS * 32; i += 256) {
            int r = i >> 5, kl = i & 31;
            int gr = row0 + r; if (gr > NN - 1) gr = NN - 1;
            As[r * 36 + kl] = A[(size_t)gr * K + kc + kl];
        }
        for (int i = tid; i < 32 * N; i += 256)
            Ws[i] = W[(size_t)kc * N + i];
        __syncthreads();
        #pragma unroll
        for (int kl = 0; kl < 32; kl += 4) {
            float4 a[4], w[4];
            #pragma unroll
            for (int i = 0; i < 4; ++i)
                a[i] = *(const float4*)&As[(4 * ty + i) * 36 + kl];
            #pragma unroll
            for (int t = 0; t < 4; ++t)
                w[t] = *(const float4*)&Ws[(kl + t) * N + 4 * tx];
            #pragma unroll
            for (int i = 0; i < 4; ++i) {
                const float* af = (const float*)&a[i];
                #pragma unroll
                for (int t = 0; t < 4; ++t) {
                    float s = af[t];
                    const float* wf = (const float*)&w[t];
                    acc[i][0] = fmaf(s, wf[0], acc[i][0]);
                    acc[i][1] = fmaf(s, wf[1], acc[i][1]);
                    acc[i][2] = fmaf(s, wf[2], acc[i][2]);
                    acc[i][3] = fmaf(s, wf[3], acc[i][3]);
                }
            }
        }
    }
}

// ---------------- pre-linear: xh = x @ W[K,64] + b; also fp16 copy ------------
__global__ __launch_bounds__(256) void k_pre(const float* __restrict__ A,
                                             const float* __restrict__ W,
                                             const float* __restrict__ b,
                                             float* __restrict__ out,
                                             __half2* __restrict__ out_h, int K) {
    __shared__ __align__(16) float As[64 * 36];
    __shared__ __align__(16) float Ws[32 * 64];
    float acc[4][4];
    int row0 = blockIdx.x * 64;
    gemm_core<64>(A, W, K, row0, As, Ws, acc);
    int tx = threadIdx.x % 16, ty = threadIdx.x / 16;
    float4 bb = *(const float4*)&b[tx * 4];
    #pragma unroll
    for (int i = 0; i < 4; ++i) {
        int row = row0 + 4 * ty + i;
        if (row < NN) {
            float4 o = { acc[i][0] + bb.x, acc[i][1] + bb.y,
                         acc[i][2] + bb.z, acc[i][3] + bb.w };
            *(float4*)&out[(size_t)row * 64 + tx * 4] = o;
            out_h[(size_t)row * 32 + 2 * tx]     = __floats2half2_rn(o.x, o.y);
            out_h[(size_t)row * 32 + 2 * tx + 1] = __floats2half2_rn(o.z, o.w);
        }
    }
}

// ---------------- GAT projection (fp16 xp) + attention scores -----------------
__global__ __launch_bounds__(256) void k_proj(const float* __restrict__ xh,
                                              const float* __restrict__ W,
                                              const float* __restrict__ att_s,
                                              const float* __restrict__ att_d,
                                              __half2* __restrict__ xp_h,
                                              float* __restrict__ a_src,
                                              float* __restrict__ a_dst) {
    __shared__ __align__(16) float As[32 * 36];
    __shared__ __align__(16) float Ws[32 * 128];
    float acc[4][4];
    int row0 = blockIdx.x * 32;
    gemm_core<128>(xh, W, 64, row0, As, Ws, acc);
    int tx = threadIdx.x % 32, ty = threadIdx.x / 32;
    int col = tx * 4, h = tx >> 4;
    float4 s4 = *(const float4*)&att_s[col];
    float4 d4 = *(const float4*)&att_d[col];
    float vs[4], vd[4];
    #pragma unroll
    for (int i = 0; i < 4; ++i) {
        int row = row0 + 4 * ty + i;
        if (row < NN) {
            xp_h[(size_t)row * 64 + 2 * tx]     = __floats2half2_rn(acc[i][0], acc[i][1]);
            xp_h[(size_t)row * 64 + 2 * tx + 1] = __floats2half2_rn(acc[i][2], acc[i][3]);
        }
        vs[i] = acc[i][0] * s4.x + acc[i][1] * s4.y + acc[i][2] * s4.z + acc[i][3] * s4.w;
        vd[i] = acc[i][0] * d4.x + acc[i][1] * d4.y + acc[i][2] * d4.z + acc[i][3] * d4.w;
    }
    #pragma unroll
    for (int off = 1; off < 16; off <<= 1) {
        #pragma unroll
        for (int i = 0; i < 4; ++i) {
            vs[i] += __shfl_xor(vs[i], off);
            vd[i] += __shfl_xor(vd[i], off);
        }
    }
    if ((tx & 15) == 0) {
        #pragma unroll
        for (int i = 0; i < 4; ++i) {
            int row = row0 + 4 * ty + i;
            if (row < NN) {
                a_src[row * 2 + h] = vs[i];
                a_dst[row * 2 + h] = vd[i];
            }
        }
    }
}

// ---------------- SG linear (64 rows/block) -----------------------------------
__global__ __launch_bounds__(256) void k_sgg(const float* __restrict__ sgh,
                                             const float* __restrict__ W,
                                             const float* __restrict__ b,
                                             float* __restrict__ xout) {
    __shared__ __align__(16) float As[64 * 36];
    __shared__ __align__(16) float Ws[32 * 64];
    float acc[4][4];
    int row0 = blockIdx.x * 64;
    gemm_core<64>(sgh, W, 64, row0, As, Ws, acc);
    int tx = threadIdx.x % 16, ty = threadIdx.x / 16;
    float4 bb = *(const float4*)&b[tx * 4];
    #pragma unroll
    for (int i = 0; i < 4; ++i) {
        int row = row0 + 4 * ty + i;
        if (row < NN) {
            float4 o;
            o.x = fmaxf(acc[i][0] + bb.x, 0.f);
            o.y = fmaxf(acc[i][1] + bb.y, 0.f);
            o.z = fmaxf(acc[i][2] + bb.z, 0.f);
            o.w = fmaxf(acc[i][3] + bb.w, 0.f);
            *(float4*)&xout[(size_t)row * 192 + 128 + tx * 4] = o;
        }
    }
}

// ---------------- classifier + log_softmax (128 rows/block) -------------------
__global__ __launch_bounds__(256) void k_cls(const float* __restrict__ x,
                                             const float* __restrict__ W,
                                             const float* __restrict__ b,
                                             float* __restrict__ out) {
    __shared__ __align__(16) float As[128 * 36];
    __shared__ __align__(16) float Ws[32 * 32];
    float acc[4][4];
    int row0 = blockIdx.x * 128;
    gemm_core<32>(x, W, 192, row0, As, Ws, acc);
    int tx = threadIdx.x % 8, ty = threadIdx.x / 8;
    float4 b4 = *(const float4*)&b[tx * 4];
    #pragma unroll
    for (int i = 0; i < 4; ++i) {
        int row = row0 + 4 * ty + i;
        float v0 = acc[i][0] + b4.x, v1 = acc[i][1] + b4.y;
        float v2 = acc[i][2] + b4.z, v3 = acc[i][3] + b4.w;
        float mx = fmaxf(fmaxf(v0, v1), fmaxf(v2, v3));
        #pragma unroll
        for (int off = 1; off < 8; off <<= 1) mx = fmaxf(mx, __shfl_xor(mx, off));
        float sm = __expf(v0 - mx) + __expf(v1 - mx) + __expf(v2 - mx) + __expf(v3 - mx);
        #pragma unroll
        for (int off = 1; off < 8; off <<= 1) sm += __shfl_xor(sm, off);
        float lg = mx + __logf(sm);
        if (row < NN) {
            float4 o = { v0 - lg, v1 - lg, v2 - lg, v3 - lg };
            *(float4*)&out[(size_t)row * 32 + tx * 4] = o;
        }
    }
}

// ---------------- fused GAT aggregation: one wave per dst node ----------------
// pass 3: lane i accumulates features {2i, 2i+1}; alpha broadcast via shuffles.
__global__ __launch_bounds__(256) void k_gat_node(const int* __restrict__ row_ptr,
                                                  const int* __restrict__ src_sorted,
                                                  const float* __restrict__ a_src,
                                                  const float* __restrict__ a_dst,
                                                  const __half2* __restrict__ xp_h,
                                                  const float* __restrict__ gb,
                                                  float* __restrict__ xout) {
    int lane = threadIdx.x & 63;
    int d = blockIdx.x * 4 + (threadIdx.x >> 6);
    if (d >= NN) return;
    int p0 = row_ptr[d], p1 = row_ptr[d + 1];
    float ad0 = a_dst[2 * d], ad1 = a_dst[2 * d + 1];

    // pass 1: segment max (lane-strided)
    float m0 = -INFINITY, m1 = -INFINITY;
    for (int e = p0 + lane; e < p1; e += 64) {
        int s = src_sorted[e];
        float v0 = a_src[2 * s] + ad0;     v0 = (v0 > 0.f) ? v0 : 0.2f * v0;
        float v1 = a_src[2 * s + 1] + ad1; v1 = (v1 > 0.f) ? v1 : 0.2f * v1;
        m0 = fmaxf(m0, v0); m1 = fmaxf(m1, v1);
    }
    #pragma unroll
    for (int off = 32; off; off >>= 1) {
        m0 = fmaxf(m0, __shfl_xor(m0, off));
        m1 = fmaxf(m1, __shfl_xor(m1, off));
    }

    // pass 2: segment sum of exp
    float s0 = 0.f, s1 = 0.f;
    for (int e = p0 + lane; e < p1; e += 64) {
        int s = src_sorted[e];
        float v0 = a_src[2 * s] + ad0;     v0 = (v0 > 0.f) ? v0 : 0.2f * v0;
        float v1 = a_src[2 * s + 1] + ad1; v1 = (v1 > 0.f) ? v1 : 0.2f * v1;
        s0 += __expf(v0 - m0); s1 += __expf(v1 - m1);
    }
    #pragma unroll
    for (int off = 32; off; off >>= 1) {
        s0 += __shfl_xor(s0, off);
        s1 += __shfl_xor(s1, off);
    }
    float inv0 = 1.f / (s0 + 1e-16f), inv1 = 1.f / (s1 + 1e-16f);

    // pass 3: chunked — each lane computes alpha for its edge once, broadcast
    float2 acc = { 0.f, 0.f };
    for (int base = p0; base < p1; base += 64) {
        int e = base + lane;
        float eal0 = 0.f, eal1 = 0.f; int es = 0;
        if (e < p1) {
            es = src_sorted[e];
            float v0 = a_src[2 * es] + ad0;     v0 = (v0 > 0.f) ? v0 : 0.2f * v0;
            float v1 = a_src[2 * es + 1] + ad1; v1 = (v1 > 0.f) ? v1 : 0.2f * v1;
            eal0 = __expf(v0 - m0) * inv0;
            eal1 = __expf(v1 - m1) * inv1;
        }
        int nn = min(64, p1 - base);
        for (int j = 0; j < nn; ++j) {
            float a0 = __shfl(eal0, j);
            float a1 = __shfl(eal1, j);
            int   s  = __shfl(es, j);
            float al = (lane < 32) ? a0 : a1;   // features 2*lane: head = lane>=32
            float2 f = __half22float2(xp_h[(size_t)s * 64 + lane]);
            acc.x = fmaf(al, f.x, acc.x);
            acc.y = fmaf(al, f.y, acc.y);
        }
    }
    float2 gb2 = ((const float2*)gb)[lane];
    float2 o = { fmaxf(acc.x + gb2.x, 0.f), fmaxf(acc.y + gb2.y, 0.f) };
    *(float2*)&xout[(size_t)d * 192 + 2 * lane] = o;
}

// ---------------- fused SG propagation: 2 edges/iter per wave -----------------
__global__ __launch_bounds__(256) void k_sg_node(const int* __restrict__ row_ptr,
                                                 const int* __restrict__ src_sorted,
                                                 const float* __restrict__ w_sorted,
                                                 const float* __restrict__ dinv,
                                                 const __half2* __restrict__ xh_h,
                                                 float* __restrict__ sgh) {
    int lane = threadIdx.x & 63;
    int d = blockIdx.x * 4 + (threadIdx.x >> 6);
    if (d >= NN) return;
    int p0 = row_ptr[d], p1 = row_ptr[d + 1];
    float did = dinv[d];
    int hf = lane >> 5, l32 = lane & 31;
    float2 acc = { 0.f, 0.f };
    for (int base = p0; base < p1; base += 2) {
        int e = base + hf;
        if (e < p1) {
            int s = src_sorted[e];
            float nrm = did * w_sorted[e] * dinv[s];
            float2 f = __half22float2(xh_h[(size_t)s * 32 + l32]);
            acc.x = fmaf(nrm, f.x, acc.x);
            acc.y = fmaf(nrm, f.y, acc.y);
        }
    }
    acc.x += __shfl_xor(acc.x, 32);
    acc.y += __shfl_xor(acc.y, 32);
    if (lane < 32)
        *(float2*)&sgh[(size_t)d * 64 + 2 * l32] = acc;
}

// ------------------------------------------------------------------------------
extern "C" void kernel_launch(void* const* d_in, const int* in_sizes, int n_in,
                              void* d_out, int out_size, void* d_ws, size_t ws_size,
                              hipStream_t stream) {
    const float* x   = (const float*)d_in[0];
    const int*   ei  = (const int*)d_in[1];
    const float* ew  = (const float*)d_in[2];
    const int* src = ei;
    const int* dst = ei + NE;

    const float* P[2][8];
    for (int l = 0; l < 2; ++l)
        for (int j = 0; j < 8; ++j)
            P[l][j] = (const float*)d_in[3 + l * 8 + j];
    const float* cls_W = (const float*)d_in[19];
    const float* cls_b = (const float*)d_in[20];

    float* ws = (float*)d_ws;
    const size_t n = NN;
    float* xh    = ws;                        // 64N  fp32
    float* u0    = ws + 64 * n;               // 64N  : xp_h (half) then sgh (fp32)
    __half2* xp_h = (__half2*)u0;
    float* sgh   = u0;
    __half2* xh_h = (__half2*)(ws + 128 * n); // 32N float-slots (64 halves/row)
    float* a_src = ws + 160 * n;              // 2N
    float* a_dst = ws + 162 * n;              // 2N
    float* dinv  = ws + 164 * n;              // N
    float* xA    = ws + 165 * n;              // 192N
    float* xB    = ws + 357 * n;              // 192N
    int*   row_ptr    = (int*)(ws + 549 * n);        // NN+1
    int*   cnt        = row_ptr + (NN + 1);          // NN (histogram, then cursor)
    int*   bsum       = cnt + NN;                    // 512
    int*   src_sorted = bsum + 512;                  // NES
    float* w_sorted   = (float*)(src_sorted + NES);  // NES

    const int TB = 256;
    int gb_edge = (NES + TB - 1) / TB;
    int gb_node = (NN + TB - 1) / TB;
    int gb_wave4 = (NN + 3) / 4;

    // ---- CSR build + degrees ----
    hipMemsetAsync(cnt, 0, NN * sizeof(int), stream);
    hipMemsetAsync(dinv, 0, n * sizeof(float), stream);
    k_histdeg<<<gb_edge, TB, 0, stream>>>(dst, ew, cnt, dinv);
    k_scanA<<<NBLK, TB, 0, stream>>>(cnt, row_ptr, bsum);
    k_scanB<<<1, 512, 0, stream>>>(bsum);
    k_scanC<<<gb_node, TB, 0, stream>>>(row_ptr, bsum);
    k_fill <<<gb_edge, TB, 0, stream>>>(src, dst, ew, row_ptr, cnt, src_sorted, w_sorted);
    k_dinv <<<gb_node, TB, 0, stream>>>(dinv);

    const float* xin = x;
    int K = FIN;
    for (int l = 0; l < 2; ++l) {
        const float* pre_W = P[l][0]; const float* pre_b = P[l][1];
        const float* gat_W = P[l][2]; const float* att_s = P[l][3];
        const float* att_d = P[l][4]; const float* gat_b = P[l][5];
        const float* sg_W  = P[l][6]; const float* sg_b  = P[l][7];
        float* xout = (l == 0) ? xA : xB;

        k_pre <<<(NN + 63) / 64, TB, 0, stream>>>(xin, pre_W, pre_b, xh, xh_h, K);
        k_proj<<<(NN + 31) / 32, TB, 0, stream>>>(xh, gat_W, att_s, att_d,
                                                  xp_h, a_src, a_dst);
        k_gat_node<<<gb_wave4, TB, 0, stream>>>(row_ptr, src_sorted, a_src, a_dst,
                                                xp_h, gat_b, xout);
        k_sg_node <<<gb_wave4, TB, 0, stream>>>(row_ptr, src_sorted, w_sorted, dinv,
                                                xh_h, sgh);
        k_sgg <<<(NN + 63) / 64, TB, 0, stream>>>(sgh, sg_W, sg_b, xout);

        xin = xout;
        K = 192;
    }

    k_cls<<<(NN + 127) / 128, TB, 0, stream>>>(xB, cls_W, cls_b, (float*)d_out);
}